// Round 13
// baseline (1931.004 us; speedup 1.0000x reference)
//
#include <hip/hip_runtime.h>

// Problem constants
#define T_SEQ 2048
#define NB 2
#define HH 16
#define M_ROWS 4096      // B*T
#define KDIM 2048        // D
#define N1B 14464        // Q(2048)+K(6144)+V(6144)+B(48)+A(16) = 14400, padded to 128
#define COL_B 14336
#define COL_A 14384
#define NCH2 1024        // C=2 chunks per (b,h)
#define CREC 48          // floats per chunk record

typedef unsigned short u16;
typedef __attribute__((ext_vector_type(8))) short bf16x8;
typedef __attribute__((ext_vector_type(4))) float f32x4;

__device__ __forceinline__ u16 f2b(float f) {
  union { float f; unsigned u; } a; a.f = f;
  unsigned u = a.u;
  u += 0x7fffu + ((u >> 16) & 1u);   // RNE
  return (u16)(u >> 16);
}
__device__ __forceinline__ float b2f(u16 s) {
  union { unsigned u; float f; } a; a.u = ((unsigned)s) << 16;
  return a.f;
}
__device__ __forceinline__ float silu_f(float y) {
  return y / (1.f + __expf(-y));
}

// 16-lane row all-reduce via DPP row_ror adds.
__device__ __forceinline__ float rowsum16(float x) {
  int xi;
  xi = __builtin_amdgcn_update_dpp(0, __float_as_int(x), 0x128, 0xf, 0xf, true); // ror:8
  x += __int_as_float(xi);
  xi = __builtin_amdgcn_update_dpp(0, __float_as_int(x), 0x124, 0xf, 0xf, true); // ror:4
  x += __int_as_float(xi);
  xi = __builtin_amdgcn_update_dpp(0, __float_as_int(x), 0x122, 0xf, 0xf, true); // ror:2
  x += __int_as_float(xi);
  xi = __builtin_amdgcn_update_dpp(0, __float_as_int(x), 0x121, 0xf, 0xf, true); // ror:1
  x += __int_as_float(xi);
  return x;
}

// async global->LDS, 16B per lane
__device__ __forceinline__ void gload_lds16(const u16* g, u16* l) {
  __builtin_amdgcn_global_load_lds(
      (const __attribute__((address_space(1))) unsigned int*)g,
      (__attribute__((address_space(3))) unsigned int*)l, 16, 0, 0);
}

#define UNPK(u, lo, hi) { lo = __uint_as_float((u) << 16); hi = __uint_as_float((u) & 0xffff0000u); }

__device__ __forceinline__ void unpk8(uint4 u, float* f) {
  UNPK(u.x, f[0], f[1]); UNPK(u.y, f[2], f[3]);
  UNPK(u.z, f[4], f[5]); UNPK(u.w, f[6], f[7]);
}

// ---------------- x -> bf16 ----------------
__global__ __launch_bounds__(256) void cvt_x_kernel(const float* __restrict__ x,
                                                    u16* __restrict__ xb) {
  int i = (blockIdx.x * 256 + threadIdx.x) * 4;
  float4 v = *(const float4*)&x[i];
  ushort4 o;
  o.x = f2b(v.x); o.y = f2b(v.y); o.z = f2b(v.z); o.w = f2b(v.w);
  *(ushort4*)&xb[i] = o;
}

// ---------------- concat-transpose [Wq|Wk|Wv|Wb|Wa] -> WcatT [N1B][K] bf16 ----------------
__global__ __launch_bounds__(256) void wcat_t_kernel(
    const float* __restrict__ Wq, const float* __restrict__ Wk,
    const float* __restrict__ Wv, const float* __restrict__ Wb,
    const float* __restrict__ Wa, u16* __restrict__ WcatT) {
  __shared__ float tile[32][33];
  int kk0 = blockIdx.x * 32;
  int n0  = blockIdx.y * 32;
  int tx = threadIdx.x, ty = threadIdx.y;
  #pragma unroll
  for (int i = 0; i < 4; i++) {
    int kk = kk0 + ty + i * 8;
    int n = n0 + tx;
    float v;
    if      (n < 2048)  v = Wq[(size_t)kk * 2048 + n];
    else if (n < 8192)  v = Wk[(size_t)kk * 6144 + (n - 2048)];
    else if (n < 14336) v = Wv[(size_t)kk * 6144 + (n - 8192)];
    else if (n < 14384) v = Wb[(size_t)kk * 48 + (n - 14336)];
    else if (n < 14400) v = Wa[(size_t)kk * 16 + (n - 14384)];
    else                v = 0.f;
    tile[ty + i * 8][tx] = v;
  }
  __syncthreads();
  #pragma unroll
  for (int i = 0; i < 4; i++) {
    int n = n0 + ty + i * 8;
    int kk = kk0 + tx;
    WcatT[(size_t)n * 2048 + kk] = f2b(tile[tx][ty + i * 8]);
  }
}

// ---------------- transpose any [2048][2048] f32 -> bf16 T ----------------
__global__ __launch_bounds__(256) void t2048_kernel(const float* __restrict__ W,
                                                    u16* __restrict__ WT) {
  __shared__ float tile[32][33];
  int kk0 = blockIdx.x * 32;
  int n0  = blockIdx.y * 32;
  int tx = threadIdx.x, ty = threadIdx.y;
  #pragma unroll
  for (int i = 0; i < 4; i++)
    tile[ty + i * 8][tx] = W[(size_t)(kk0 + ty + i * 8) * 2048 + (n0 + tx)];
  __syncthreads();
  #pragma unroll
  for (int i = 0; i < 4; i++)
    WT[(size_t)(n0 + ty + i * 8) * 2048 + (kk0 + tx)] = f2b(tile[tx][ty + i * 8]);
}

// ---------------- bf16 MFMA GEMM (m97 structure) ----------------
template<typename OT>
__global__ __launch_bounds__(256) void gemm_bt_kernel(
    const u16* __restrict__ A, const u16* __restrict__ BT, OT* __restrict__ C,
    int M, int N, int K) {
  __shared__ u16 As[128 * 32];
  __shared__ u16 Bs[128 * 32];
  int tid = threadIdx.x;
  int wave = tid >> 6, lane = tid & 63;
  int wr = (wave >> 1) * 64, wc = (wave & 1) * 64;
  int l15 = lane & 15, l4 = lane >> 4;
  size_t mt = (size_t)blockIdx.y * 128, nt = (size_t)blockIdx.x * 128;
  f32x4 acc[4][4] = {};

  int srow = wave * 32 + (lane >> 2);
  int scol = (lane & 3) * 8;
  const u16* gA0 = &A [(mt + srow) * (size_t)K + scol];
  const u16* gA1 = &A [(mt + srow + 16) * (size_t)K + scol];
  const u16* gB0 = &BT[(nt + srow) * (size_t)K + scol];
  const u16* gB1 = &BT[(nt + srow + 16) * (size_t)K + scol];
  u16* lA0 = &As[wave * 1024];
  u16* lA1 = &As[wave * 1024 + 512];
  u16* lB0 = &Bs[wave * 1024];
  u16* lB1 = &Bs[wave * 1024 + 512];

  for (int k0 = 0; k0 < K; k0 += 32) {
    gload_lds16(gA0 + k0, lA0);
    gload_lds16(gA1 + k0, lA1);
    gload_lds16(gB0 + k0, lB0);
    gload_lds16(gB1 + k0, lB1);
    __syncthreads();
    bf16x8 af[4], bvf[4];
    #pragma unroll
    for (int m = 0; m < 4; m++) af[m] = *(const bf16x8*)&As[(wr + m * 16 + l15) * 32 + l4 * 8];
    #pragma unroll
    for (int n = 0; n < 4; n++) bvf[n] = *(const bf16x8*)&Bs[(wc + n * 16 + l15) * 32 + l4 * 8];
    #pragma unroll
    for (int m = 0; m < 4; m++)
      #pragma unroll
      for (int n = 0; n < 4; n++)
        acc[m][n] = __builtin_amdgcn_mfma_f32_16x16x32_bf16(af[m], bvf[n], acc[m][n], 0, 0, 0);
    __syncthreads();
  }
  #pragma unroll
  for (int m = 0; m < 4; m++)
    #pragma unroll
    for (int n = 0; n < 4; n++)
      #pragma unroll
      for (int r = 0; r < 4; r++) {
        size_t row = mt + wr + m * 16 + l4 * 4 + r;
        size_t col = nt + wc + n * 16 + l15;
        if constexpr (sizeof(OT) == 2) C[row * (size_t)N + col] = f2b(acc[m][n][r]);
        else                           C[row * (size_t)N + col] = acc[m][n][r];
      }
}

// ---------------- conv + SiLU + l2norm + beta/e  (r9, verified) ----------------
__global__ __launch_bounds__(256) void conv_act_kernel(
    const u16* __restrict__ P,
    const float* __restrict__ conv_q, const float* __restrict__ conv_k,
    const float* __restrict__ conv_v, const float* __restrict__ A_log,
    const float* __restrict__ dt_bias,
    u16* __restrict__ qs, u16* __restrict__ ks, u16* __restrict__ vs,
    float* __restrict__ betag) {
  __shared__ float buf[14336];
  __shared__ float partial[256];
  __shared__ float scl[64];
  int row = blockIdx.x;
  int t = row & (T_SEQ - 1);
  int tid = threadIdx.x;
  const size_t prow = (size_t)row * N1B;

  for (int cb = tid; cb < 1792; cb += 256) {
    int ch = cb * 8;
    float x0[8], x1[8], x2[8], x3[8];
    #pragma unroll
    for (int j = 0; j < 8; j++) { x1[j] = 0.f; x2[j] = 0.f; x3[j] = 0.f; }
    unpk8(*(const uint4*)&P[prow + ch], x0);
    if (t >= 1) unpk8(*(const uint4*)&P[prow - N1B + ch], x1);
    if (t >= 2) unpk8(*(const uint4*)&P[prow - 2 * N1B + ch], x2);
    if (t >= 3) unpk8(*(const uint4*)&P[prow - 3 * N1B + ch], x3);
    const float* w8;
    if (ch < 2048)      w8 = &conv_q[ch * 4];
    else if (ch < 8192) w8 = &conv_k[(ch - 2048) * 4];
    else                w8 = &conv_v[(ch - 8192) * 4];
    float r[8];
    #pragma unroll
    for (int j = 0; j < 8; j++) {
      float4 w = *(const float4*)&w8[j * 4];
      float acc = w.w * x0[j] + w.z * x1[j] + w.y * x2[j] + w.x * x3[j];
      r[j] = silu_f(acc);
    }
    *(float4*)&buf[ch]     = make_float4(r[0], r[1], r[2], r[3]);
    *(float4*)&buf[ch + 4] = make_float4(r[4], r[5], r[6], r[7]);
  }
  __syncthreads();
  {
    int vec = tid >> 2, part = tid & 3;
    int base = (vec < 16) ? vec * 128 : 2048 + (vec - 16) * 128;
    float s = 0.f;
    #pragma unroll
    for (int i = 0; i < 8; i++) {
      float4 v4 = *(const float4*)&buf[base + part * 32 + i * 4];
      s += v4.x * v4.x + v4.y * v4.y + v4.z * v4.z + v4.w * v4.w;
    }
    partial[tid] = s;
  }
  __syncthreads();
  if (tid < 64) {
    float tot = partial[tid * 4] + partial[tid * 4 + 1] + partial[tid * 4 + 2] + partial[tid * 4 + 3];
    float sc = rsqrtf(tot + 1e-6f);
    if (tid < 16) sc *= 0.08838834764831845f;
    scl[tid] = sc;
  }
  __syncthreads();
  for (int cb = tid; cb < 1792; cb += 256) {
    int ch = cb * 8;
    float4 y0 = *(const float4*)&buf[ch];
    float4 y1 = *(const float4*)&buf[ch + 4];
    float sc; u16* dst;
    if (ch < 2048)      { sc = scl[ch >> 7];              dst = &qs[(size_t)row * 2048 + ch]; }
    else if (ch < 8192) { int r = ch - 2048; sc = scl[16 + (r >> 7)]; dst = &ks[(size_t)row * 6144 + r]; }
    else                { int r = ch - 8192; sc = 1.f;    dst = &vs[(size_t)row * 6144 + r]; }
    ushort4 s0, s1;
    s0.x = f2b(y0.x * sc); s0.y = f2b(y0.y * sc); s0.z = f2b(y0.z * sc); s0.w = f2b(y0.w * sc);
    s1.x = f2b(y1.x * sc); s1.y = f2b(y1.y * sc); s1.z = f2b(y1.z * sc); s1.w = f2b(y1.w * sc);
    *(ushort4*)dst = s0;
    *(ushort4*)(dst + 4) = s1;
  }
  if (tid < 16) {
    int h = tid;
    float b0 = b2f(P[prow + COL_B + h]);
    float b1 = b2f(P[prow + COL_B + 16 + h]);
    float b2 = b2f(P[prow + COL_B + 32 + h]);
    float pa = b2f(P[prow + COL_A + h]) + dt_bias[h];
    float sp = (pa > 20.f) ? pa : log1pf(__expf(pa));
    float4 bg;
    bg.x = 2.f / (1.f + __expf(-b0));
    bg.y = 2.f / (1.f + __expf(-b1));
    bg.z = 2.f / (1.f + __expf(-b2));
    bg.w = __expf(-__expf(A_log[h]) * sp);   // e = exp(g)
    *(float4*)&betag[((size_t)row * 16 + h) * 4] = bg;
  }
}

// ---------------- K1: per-chunk (C=2) WY precompute -------------------------------
// Each block covers 4 timesteps = 2 chunks. Gram of [k rows 0..11, q rows 12..15]
// via 4 MFMA (layout verified in r11). Record (48 f) per chunk:
// [0:15) Tinv strictly-lower packed (idx j*(j-1)/2+i), [15:27) G[2][6],
// [27:33) beta_j*Gamma_{s_j}, [33:39) d_j, [39:45) beta_j, [45] G0, [46] G1, [47] pad
__global__ __launch_bounds__(64) void k1_kernel(
    const u16* __restrict__ qs, const u16* __restrict__ ks,
    const float* __restrict__ betag, float* __restrict__ chunkbuf) {
  int blk = blockIdx.x;
  int cc4 = blk & 511, bh = blk >> 9;
  int h = bh & 15, b = bh >> 4;
  int lane = threadIdx.x;
  int t0 = cc4 * 4;
  size_t bT = (size_t)b * T_SEQ;
  __shared__ u16 m16[16 * 128];
  __shared__ float gram[16][16];
  __shared__ float sc[16];   // [0:12) beta (idx 3*dt+i), [12:16) e_t

  #pragma unroll
  for (int it = 0; it < 4; it++) {
    int seg = it * 64 + lane;
    int row = seg >> 4, part = seg & 15;
    const u16* src;
    if (row < 12) src = &ks[(bT + t0 + row / 3) * 6144 + (row % 3) * 2048 + h * 128 + part * 8];
    else          src = &qs[(bT + t0 + (row - 12)) * 2048 + h * 128 + part * 8];
    *(uint4*)&m16[row * 128 + part * 8] = *(const uint4*)src;
  }
  if (lane < 4) {
    float4 bg = *(const float4*)&betag[((bT + t0 + lane) * 16 + h) * 4];
    sc[lane * 3 + 0] = bg.x; sc[lane * 3 + 1] = bg.y; sc[lane * 3 + 2] = bg.z;
    sc[12 + lane] = bg.w;
  }
  __syncthreads();

  int l15 = lane & 15, l4 = lane >> 4;
  f32x4 acc = {};
  #pragma unroll
  for (int kk = 0; kk < 4; kk++) {
    bf16x8 f = *(const bf16x8*)&m16[l15 * 128 + kk * 32 + l4 * 8];
    acc = __builtin_amdgcn_mfma_f32_16x16x32_bf16(f, f, acc, 0, 0, 0);
  }
  #pragma unroll
  for (int r = 0; r < 4; r++) gram[l4 * 4 + r][l15] = acc[r];
  __syncthreads();

  if (lane < 12) {
    int X = lane / 6, col = lane % 6;
    float eX1 = sc[12 + 2 * X + 1];
    float Gm0 = sc[12 + 2 * X];
    float Gm1 = Gm0 * eX1;
    float* out = &chunkbuf[((size_t)bh * NCH2 + cc4 * 2 + X) * CREC];
    // Tinv column col: forward substitution on (I+M), M[j][p] = beta_j*c[s_p][s_j]*gram
    float x[6];
    #pragma unroll
    for (int j = 0; j < 6; j++) {
      float s = (j == col) ? 1.f : 0.f;
      #pragma unroll
      for (int p = 0; p < j; p++) {
        float cde = ((p / 3) == (j / 3)) ? 1.f : eX1;
        s -= sc[6 * X + j] * cde * gram[6 * X + j][6 * X + p] * x[p];
      }
      x[j] = (j < col) ? 0.f : s;
    }
    #pragma unroll
    for (int j = 1; j < 6; j++)
      if (j > col) out[j * (j - 1) / 2 + col] = x[j];
    // per-j scalars (j = col)
    int j = col, sj = j / 3;
    float bj = sc[6 * X + j];
    out[27 + j] = bj * ((sj == 0) ? Gm0 : Gm1);
    out[33 + j] = (sj == 0) ? eX1 : 1.f;
    out[39 + j] = bj;
    #pragma unroll
    for (int t = 0; t < 2; t++) {
      float g = 0.f;
      if (sj <= t) g = ((sj == t) ? 1.f : eX1) * gram[12 + 2 * X + t][6 * X + j];
      out[15 + t * 6 + j] = g;
    }
    if (col == 0) { out[45] = Gm0; out[46] = Gm1; out[47] = 0.f; }
  }
}

// ---------------- chunked (C=2) sequential scan -----------------------------------
// Grid: (b*H + h)*8 + vchunk ; 256 threads = 16 columns x 16 k-lanes. 1024 chunk iters.
// Records read with block-uniform addresses -> scalar cache; no LDS, no barriers.
#define DOT8(KV, OUT) { \
  float k0_,k1_,k2_,k3_,k4_,k5_,k6_,k7_; \
  UNPK((KV).x,k0_,k1_); UNPK((KV).y,k2_,k3_); \
  UNPK((KV).z,k4_,k5_); UNPK((KV).w,k6_,k7_); \
  float d_ = ((k0_*S0+k1_*S1)+(k2_*S2+k3_*S3))+((k4_*S4+k5_*S5)+(k6_*S6+k7_*S7)); \
  OUT = rowsum16(d_); }

#define AXPY8(KV, W) { \
  float k0_,k1_,k2_,k3_,k4_,k5_,k6_,k7_; \
  UNPK((KV).x,k0_,k1_); UNPK((KV).y,k2_,k3_); \
  UNPK((KV).z,k4_,k5_); UNPK((KV).w,k6_,k7_); \
  float w_ = (W); \
  S0 += k0_*w_; S1 += k1_*w_; S2 += k2_*w_; S3 += k3_*w_; \
  S4 += k4_*w_; S5 += k5_*w_; S6 += k6_*w_; S7 += k7_*w_; }

#define LOADC(KR, QR, VF, CC) { \
  int t0_ = (CC) * 2; \
  _Pragma("unroll") \
  for (int j = 0; j < 6; j++) \
    KR[j] = *(const uint4*)&ks[kbase + (size_t)(t0_ + j / 3) * 6144 + (j % 3) * 2048]; \
  _Pragma("unroll") \
  for (int t = 0; t < 2; t++) \
    QR[t] = *(const uint4*)&qs[qbase + (size_t)(t0_ + t) * 2048]; \
  _Pragma("unroll") \
  for (int j = 0; j < 6; j++) \
    VF[j] = b2f(vs[vbase + (size_t)(t0_ + j / 3) * 6144 + (j % 3) * 2048]); }

#define COMPC(KR, QR, VF, CC) { \
  const float* cb_ = cbbase + (size_t)(CC) * CREC; \
  float p0_, p1_, p2_, p3_, p4_, p5_, pq0_, pq1_; \
  DOT8(KR[0], p0_); DOT8(KR[1], p1_); DOT8(KR[2], p2_); \
  DOT8(KR[3], p3_); DOT8(KR[4], p4_); DOT8(KR[5], p5_); \
  DOT8(QR[0], pq0_); DOT8(QR[1], pq1_); \
  float bv0_ = cb_[39] * VF[0] - cb_[27] * p0_; \
  float bv1_ = cb_[40] * VF[1] - cb_[28] * p1_; \
  float bv2_ = cb_[41] * VF[2] - cb_[29] * p2_; \
  float bv3_ = cb_[42] * VF[3] - cb_[30] * p3_; \
  float bv4_ = cb_[43] * VF[4] - cb_[31] * p4_; \
  float bv5_ = cb_[44] * VF[5] - cb_[32] * p5_; \
  float u0_ = bv0_; \
  float u1_ = bv1_ + cb_[0] * bv0_; \
  float u2_ = bv2_ + cb_[1] * bv0_ + cb_[2] * bv1_; \
  float u3_ = bv3_ + cb_[3] * bv0_ + cb_[4] * bv1_ + cb_[5] * bv2_; \
  float u4_ = bv4_ + cb_[6] * bv0_ + cb_[7] * bv1_ + cb_[8] * bv2_ + cb_[9] * bv3_; \
  float u5_ = bv5_ + cb_[10] * bv0_ + cb_[11] * bv1_ + cb_[12] * bv2_ + cb_[13] * bv3_ + cb_[14] * bv4_; \
  float G1_ = cb_[46]; \
  S0 *= G1_; S1 *= G1_; S2 *= G1_; S3 *= G1_; \
  S4 *= G1_; S5 *= G1_; S6 *= G1_; S7 *= G1_; \
  AXPY8(KR[0], cb_[33] * u0_); AXPY8(KR[1], cb_[34] * u1_); AXPY8(KR[2], cb_[35] * u2_); \
  AXPY8(KR[3], cb_[36] * u3_); AXPY8(KR[4], cb_[37] * u4_); AXPY8(KR[5], cb_[38] * u5_); \
  float oA_ = cb_[45] * pq0_ + cb_[15] * u0_ + cb_[16] * u1_ + cb_[17] * u2_ \
            + cb_[18] * u3_ + cb_[19] * u4_ + cb_[20] * u5_; \
  float oB_ = cb_[46] * pq1_ + cb_[21] * u0_ + cb_[22] * u1_ + cb_[23] * u2_ \
            + cb_[24] * u3_ + cb_[25] * u4_ + cb_[26] * u5_; \
  if (kl == 0) { \
    os[obase + (size_t)(2 * (CC)) * 2048] = oA_; \
    os[obase + (size_t)(2 * (CC) + 1) * 2048] = oB_; } }

__global__ __launch_bounds__(256) void scan_kernel(
    const u16* __restrict__ qs, const u16* __restrict__ ks,
    const u16* __restrict__ vs, const float* __restrict__ chunkbuf,
    float* __restrict__ os) {
  int blk = blockIdx.x;
  int vchunk = blk & 7, bh = blk >> 3;
  int h = bh & 15, b = bh >> 4;
  int tid = threadIdx.x;
  int c = tid >> 4, kl = tid & 15;
  int v = vchunk * 16 + c;
  float S0 = 0, S1 = 0, S2 = 0, S3 = 0, S4 = 0, S5 = 0, S6 = 0, S7 = 0;

  size_t bT = (size_t)b * T_SEQ;
  const size_t qbase = bT * 2048 + h * 128 + kl * 8;
  const size_t kbase = bT * 6144 + h * 128 + kl * 8;
  const size_t vbase = bT * 6144 + h * 128 + v;
  const size_t obase = bT * 2048 + h * 128 + v;
  const float* cbbase = &chunkbuf[(size_t)bh * NCH2 * CREC];

  uint4 krA[6], krB[6], qrA[2], qrB[2];
  float vfA[6], vfB[6];

  LOADC(krA, qrA, vfA, 0);
  for (int cc = 0; cc < NCH2; cc += 2) {
    LOADC(krB, qrB, vfB, cc + 1);
    COMPC(krA, qrA, vfA, cc);
    int nn = (cc + 2 < NCH2) ? cc + 2 : NCH2 - 1;
    LOADC(krA, qrA, vfA, nn);
    COMPC(krB, qrB, vfB, cc + 1);
  }
}

// ---------------- output RMS-norm * norm_w * silu(gate) -> bf16 ----------------
__global__ __launch_bounds__(256) void norm_gate_kernel(
    const float* __restrict__ os, const u16* __restrict__ gb,
    const float* __restrict__ norm_w, u16* __restrict__ ob) {
  int row = blockIdx.x, tid = threadIdx.x;
  int hh = tid >> 4, l = tid & 15;
  size_t obase = (size_t)row * 2048 + hh * 128 + l * 8;
  float4 o0 = *(const float4*)&os[obase];
  float4 o1 = *(const float4*)&os[obase + 4];
  float ss = o0.x * o0.x + o0.y * o0.y + o0.z * o0.z + o0.w * o0.w
           + o1.x * o1.x + o1.y * o1.y + o1.z * o1.z + o1.w * o1.w;
  ss = rowsum16(ss);
  float sc = rsqrtf(ss * (1.f / 128.f) + 1e-5f);
  uint4 gv = *(const uint4*)&gb[obase];
  float4 w0 = *(const float4*)&norm_w[l * 8];
  float4 w1 = *(const float4*)&norm_w[l * 8 + 4];
  float gv0 = silu_f(b2f((u16)(gv.x & 0xffffu))), gv1 = silu_f(b2f((u16)(gv.x >> 16)));
  float gv2 = silu_f(b2f((u16)(gv.y & 0xffffu))), gv3 = silu_f(b2f((u16)(gv.y >> 16)));
  float gv4 = silu_f(b2f((u16)(gv.z & 0xffffu))), gv5 = silu_f(b2f((u16)(gv.z >> 16)));
  float gv6 = silu_f(b2f((u16)(gv.w & 0xffffu))), gv7 = silu_f(b2f((u16)(gv.w >> 16)));
  ushort4 r0, r1;
  r0.x = f2b(o0.x * sc * w0.x * gv0);
  r0.y = f2b(o0.y * sc * w0.y * gv1);
  r0.z = f2b(o0.z * sc * w0.z * gv2);
  r0.w = f2b(o0.w * sc * w0.w * gv3);
  r1.x = f2b(o1.x * sc * w1.x * gv4);
  r1.y = f2b(o1.y * sc * w1.y * gv5);
  r1.z = f2b(o1.z * sc * w1.z * gv6);
  r1.w = f2b(o1.w * sc * w1.w * gv7);
  *(ushort4*)&ob[obase] = r0;
  *(ushort4*)&ob[obase + 4] = r1;
}

extern "C" void kernel_launch(void* const* d_in, const int* in_sizes, int n_in,
                              void* d_out, int out_size, void* d_ws, size_t ws_size,
                              hipStream_t stream) {
  (void)in_sizes; (void)n_in; (void)out_size; (void)ws_size;
  const float* x       = (const float*)d_in[0];
  const float* Wq      = (const float*)d_in[3];
  const float* Wk      = (const float*)d_in[4];
  const float* Wv      = (const float*)d_in[5];
  const float* Wb      = (const float*)d_in[6];
  const float* Wa      = (const float*)d_in[7];
  const float* A_log   = (const float*)d_in[8];
  const float* dt_bias = (const float*)d_in[9];
  const float* conv_q  = (const float*)d_in[10];
  const float* conv_k  = (const float*)d_in[11];
  const float* conv_v  = (const float*)d_in[12];
  const float* Wg      = (const float*)d_in[13];
  const float* norm_w  = (const float*)d_in[14];
  const float* Wo      = (const float*)d_in[15];

  // ---- workspace layout with lifetime-based reuse (~250.5 MB peak) ----
  char* ws = (char*)d_ws;
  constexpr size_t SZ_XB    = (size_t)M_ROWS * KDIM * 2;      //  16 MB
  constexpr size_t SZ_WCAT  = (size_t)N1B * KDIM * 2;         //  56.5 MB (then ks)
  constexpr size_t SZ_P1    = (size_t)M_ROWS * N1B * 2;       // 113 MB   (then os/WgT/gb/ob/WoT/chunkbuf)
  constexpr size_t SZ_QS    = (size_t)M_ROWS * 2048 * 2;      //  16 MB
  constexpr size_t SZ_VS    = (size_t)M_ROWS * 6144 * 2;      //  48 MB

  u16*   xb    = (u16*)(ws);
  u16*   WcatT = (u16*)(ws + SZ_XB);
  u16*   P1    = (u16*)(ws + SZ_XB + SZ_WCAT);
  u16*   qs    = (u16*)(ws + SZ_XB + SZ_WCAT + SZ_P1);
  u16*   vs    = (u16*)(ws + SZ_XB + SZ_WCAT + SZ_P1 + SZ_QS);
  float* betag = (float*)(ws + SZ_XB + SZ_WCAT + SZ_P1 + SZ_QS + SZ_VS);  // 1 MB
  // aliases (sequential stream => safe):
  u16*   ks  = WcatT;                                   // after gemm1, WcatT dead (48 <= 56.5 MB)
  char*  rp  = (char*)P1;                               // after conv_act, P1 dead
  float* os  = (float*)(rp);                            // 32 MB
  u16*   WgT = (u16*)(rp + 33554432);                   // 8 MB
  u16*   gb  = (u16*)(rp + 33554432 + 8388608);         // 16 MB
  u16*   ob  = (u16*)(rp + 33554432 + 8388608 + 16777216);            // 16 MB
  u16*   WoT = (u16*)(rp + 33554432 + 8388608 + 16777216 + 16777216); // 8 MB
  float* chunkbuf = (float*)(rp + (size_t)80 * 1024 * 1024);          // 6.3 MB (80..86.3 < 113)

  cvt_x_kernel<<<(M_ROWS * KDIM) / 1024, 256, 0, stream>>>(x, xb);
  wcat_t_kernel<<<dim3(64, N1B / 32), dim3(32, 8), 0, stream>>>(Wq, Wk, Wv, Wb, Wa, WcatT);
  gemm_bt_kernel<u16><<<dim3(N1B / 128, M_ROWS / 128), 256, 0, stream>>>(xb, WcatT, P1,
                                                                         M_ROWS, N1B, KDIM);
  conv_act_kernel<<<M_ROWS, 256, 0, stream>>>(P1, conv_q, conv_k, conv_v, A_log, dt_bias,
                                              qs, ks, vs, betag);
  k1_kernel<<<NB * HH * 512, 64, 0, stream>>>(qs, ks, betag, chunkbuf);
  scan_kernel<<<NB * HH * 8, 256, 0, stream>>>(qs, ks, vs, chunkbuf, os);
  t2048_kernel<<<dim3(64, 64), dim3(32, 8), 0, stream>>>(Wg, WgT);
  gemm_bt_kernel<u16><<<dim3(2048 / 128, M_ROWS / 128), 256, 0, stream>>>(xb, WgT, gb,
                                                                          M_ROWS, 2048, KDIM);
  norm_gate_kernel<<<M_ROWS, 256, 0, stream>>>(os, gb, norm_w, ob);
  t2048_kernel<<<dim3(64, 64), dim3(32, 8), 0, stream>>>(Wo, WoT);
  gemm_bt_kernel<float><<<dim3(2048 / 128, M_ROWS / 128), 256, 0, stream>>>(ob, WoT, (float*)d_out,
                                                                            M_ROWS, 2048, KDIM);
}

// Round 14
// 1489.501 us; speedup vs baseline: 1.2964x; 1.2964x over previous
//
#include <hip/hip_runtime.h>

// Problem constants
#define T_SEQ 2048
#define NB 2
#define HH 16
#define M_ROWS 4096      // B*T
#define KDIM 2048        // D
#define N1B 14464        // Q(2048)+K(6144)+V(6144)+B(48)+A(16) = 14400, padded to 128
#define COL_B 14336
#define COL_A 14384

typedef unsigned short u16;
typedef __attribute__((ext_vector_type(8))) short bf16x8;
typedef __attribute__((ext_vector_type(4))) float f32x4;

__device__ __forceinline__ u16 f2b(float f) {
  union { float f; unsigned u; } a; a.f = f;
  unsigned u = a.u;
  u += 0x7fffu + ((u >> 16) & 1u);   // RNE
  return (u16)(u >> 16);
}
__device__ __forceinline__ float b2f(u16 s) {
  union { unsigned u; float f; } a; a.u = ((unsigned)s) << 16;
  return a.f;
}
__device__ __forceinline__ float silu_f(float y) {
  return y / (1.f + __expf(-y));
}

// 16-lane row reduction via DPP row_ror adds (VALU latency, no LDS round-trip).
__device__ __forceinline__ float rowsum16(float x) {
  int xi;
  xi = __builtin_amdgcn_update_dpp(0, __float_as_int(x), 0x128, 0xf, 0xf, true); // ror:8
  x += __int_as_float(xi);
  xi = __builtin_amdgcn_update_dpp(0, __float_as_int(x), 0x124, 0xf, 0xf, true); // ror:4
  x += __int_as_float(xi);
  xi = __builtin_amdgcn_update_dpp(0, __float_as_int(x), 0x122, 0xf, 0xf, true); // ror:2
  x += __int_as_float(xi);
  xi = __builtin_amdgcn_update_dpp(0, __float_as_int(x), 0x121, 0xf, 0xf, true); // ror:1
  x += __int_as_float(xi);
  return x;
}

// async global->LDS, 16B per lane; LDS dest is wave-uniform base + lane*16
__device__ __forceinline__ void gload_lds16(const u16* g, u16* l) {
  __builtin_amdgcn_global_load_lds(
      (const __attribute__((address_space(1))) unsigned int*)g,
      (__attribute__((address_space(3))) unsigned int*)l, 16, 0, 0);
}

#define UNPK(u, lo, hi) { lo = __uint_as_float((u) << 16); hi = __uint_as_float((u) & 0xffff0000u); }

__device__ __forceinline__ void unpk8(uint4 u, float* f) {
  UNPK(u.x, f[0], f[1]); UNPK(u.y, f[2], f[3]);
  UNPK(u.z, f[4], f[5]); UNPK(u.w, f[6], f[7]);
}

// ---------------- x -> bf16 ----------------
__global__ __launch_bounds__(256) void cvt_x_kernel(const float* __restrict__ x,
                                                    u16* __restrict__ xb) {
  int i = (blockIdx.x * 256 + threadIdx.x) * 4;
  float4 v = *(const float4*)&x[i];
  ushort4 o;
  o.x = f2b(v.x); o.y = f2b(v.y); o.z = f2b(v.z); o.w = f2b(v.w);
  *(ushort4*)&xb[i] = o;
}

// ---------------- concat-transpose [Wq|Wk|Wv|Wb|Wa] -> WcatT [N1B][K] bf16 ----------------
__global__ __launch_bounds__(256) void wcat_t_kernel(
    const float* __restrict__ Wq, const float* __restrict__ Wk,
    const float* __restrict__ Wv, const float* __restrict__ Wb,
    const float* __restrict__ Wa, u16* __restrict__ WcatT) {
  __shared__ float tile[32][33];
  int kk0 = blockIdx.x * 32;   // over K (2048)
  int n0  = blockIdx.y * 32;   // over N1B (14464)
  int tx = threadIdx.x, ty = threadIdx.y;   // 32 x 8
  #pragma unroll
  for (int i = 0; i < 4; i++) {
    int kk = kk0 + ty + i * 8;
    int n = n0 + tx;
    float v;
    if      (n < 2048)  v = Wq[(size_t)kk * 2048 + n];
    else if (n < 8192)  v = Wk[(size_t)kk * 6144 + (n - 2048)];
    else if (n < 14336) v = Wv[(size_t)kk * 6144 + (n - 8192)];
    else if (n < 14384) v = Wb[(size_t)kk * 48 + (n - 14336)];
    else if (n < 14400) v = Wa[(size_t)kk * 16 + (n - 14384)];
    else                v = 0.f;
    tile[ty + i * 8][tx] = v;
  }
  __syncthreads();
  #pragma unroll
  for (int i = 0; i < 4; i++) {
    int n = n0 + ty + i * 8;
    int kk = kk0 + tx;
    WcatT[(size_t)n * 2048 + kk] = f2b(tile[tx][ty + i * 8]);
  }
}

// ---------------- transpose body: [2048][2048] f32 -> bf16 T (tx in [0,32), ty in [0,8)) ----
__device__ __forceinline__ void t2048_body(const float* __restrict__ W,
                                           u16* __restrict__ WT,
                                           int kk0, int n0, int tx, int ty) {
  __shared__ float tile[32][33];
  #pragma unroll
  for (int i = 0; i < 4; i++)
    tile[ty + i * 8][tx] = W[(size_t)(kk0 + ty + i * 8) * 2048 + (n0 + tx)];
  __syncthreads();
  #pragma unroll
  for (int i = 0; i < 4; i++)
    WT[(size_t)(n0 + ty + i * 8) * 2048 + (kk0 + tx)] = f2b(tile[tx][ty + i * 8]);
}

__global__ __launch_bounds__(256) void t2048_kernel(const float* __restrict__ W,
                                                    u16* __restrict__ WT) {
  t2048_body(W, WT, blockIdx.x * 32, blockIdx.y * 32, threadIdx.x, threadIdx.y);
}

// ---------------- bf16 MFMA GEMM body (m97 structure) ----------------
template<typename OT>
__device__ __forceinline__ void gemm_body(
    const u16* __restrict__ A, const u16* __restrict__ BT, OT* __restrict__ C,
    int M, int N, int K, int bx, int by, int tid) {
  __shared__ u16 As[128 * 32];
  __shared__ u16 Bs[128 * 32];
  int wave = tid >> 6, lane = tid & 63;
  int wr = (wave >> 1) * 64, wc = (wave & 1) * 64;
  int l15 = lane & 15, l4 = lane >> 4;
  size_t mt = (size_t)by * 128, nt = (size_t)bx * 128;
  f32x4 acc[4][4] = {};

  int srow = wave * 32 + (lane >> 2);
  int scol = (lane & 3) * 8;
  const u16* gA0 = &A [(mt + srow) * (size_t)K + scol];
  const u16* gA1 = &A [(mt + srow + 16) * (size_t)K + scol];
  const u16* gB0 = &BT[(nt + srow) * (size_t)K + scol];
  const u16* gB1 = &BT[(nt + srow + 16) * (size_t)K + scol];
  u16* lA0 = &As[wave * 1024];
  u16* lA1 = &As[wave * 1024 + 512];
  u16* lB0 = &Bs[wave * 1024];
  u16* lB1 = &Bs[wave * 1024 + 512];

  for (int k0 = 0; k0 < K; k0 += 32) {
    gload_lds16(gA0 + k0, lA0);
    gload_lds16(gA1 + k0, lA1);
    gload_lds16(gB0 + k0, lB0);
    gload_lds16(gB1 + k0, lB1);
    __syncthreads();
    bf16x8 af[4], bvf[4];
    #pragma unroll
    for (int m = 0; m < 4; m++) af[m] = *(const bf16x8*)&As[(wr + m * 16 + l15) * 32 + l4 * 8];
    #pragma unroll
    for (int n = 0; n < 4; n++) bvf[n] = *(const bf16x8*)&Bs[(wc + n * 16 + l15) * 32 + l4 * 8];
    #pragma unroll
    for (int m = 0; m < 4; m++)
      #pragma unroll
      for (int n = 0; n < 4; n++)
        acc[m][n] = __builtin_amdgcn_mfma_f32_16x16x32_bf16(af[m], bvf[n], acc[m][n], 0, 0, 0);
    __syncthreads();
  }
  #pragma unroll
  for (int m = 0; m < 4; m++)
    #pragma unroll
    for (int n = 0; n < 4; n++)
      #pragma unroll
      for (int r = 0; r < 4; r++) {
        size_t row = mt + wr + m * 16 + l4 * 4 + r;
        size_t col = nt + wc + n * 16 + l15;
        if constexpr (sizeof(OT) == 2) C[row * (size_t)N + col] = f2b(acc[m][n][r]);
        else                           C[row * (size_t)N + col] = acc[m][n][r];
      }
}

template<typename OT>
__global__ __launch_bounds__(256) void gemm_bt_kernel(
    const u16* __restrict__ A, const u16* __restrict__ BT, OT* __restrict__ C,
    int M, int N, int K) {
  gemm_body<OT>(A, BT, C, M, N, K, blockIdx.x, blockIdx.y, threadIdx.x);
}

// ---------------- conv + SiLU + l2norm + beta/e  (r9, verified) ----------------
__global__ __launch_bounds__(256) void conv_act_kernel(
    const u16* __restrict__ P,
    const float* __restrict__ conv_q, const float* __restrict__ conv_k,
    const float* __restrict__ conv_v, const float* __restrict__ A_log,
    const float* __restrict__ dt_bias,
    u16* __restrict__ qs, u16* __restrict__ ks, u16* __restrict__ vs,
    float* __restrict__ betag) {
  __shared__ float buf[14336];
  __shared__ float partial[256];
  __shared__ float scl[64];
  int row = blockIdx.x;
  int t = row & (T_SEQ - 1);
  int tid = threadIdx.x;
  const size_t prow = (size_t)row * N1B;

  for (int cb = tid; cb < 1792; cb += 256) {
    int ch = cb * 8;
    float x0[8], x1[8], x2[8], x3[8];
    #pragma unroll
    for (int j = 0; j < 8; j++) { x1[j] = 0.f; x2[j] = 0.f; x3[j] = 0.f; }
    unpk8(*(const uint4*)&P[prow + ch], x0);
    if (t >= 1) unpk8(*(const uint4*)&P[prow - N1B + ch], x1);
    if (t >= 2) unpk8(*(const uint4*)&P[prow - 2 * N1B + ch], x2);
    if (t >= 3) unpk8(*(const uint4*)&P[prow - 3 * N1B + ch], x3);
    const float* w8;
    if (ch < 2048)      w8 = &conv_q[ch * 4];
    else if (ch < 8192) w8 = &conv_k[(ch - 2048) * 4];
    else                w8 = &conv_v[(ch - 8192) * 4];
    float r[8];
    #pragma unroll
    for (int j = 0; j < 8; j++) {
      float4 w = *(const float4*)&w8[j * 4];
      float acc = w.w * x0[j] + w.z * x1[j] + w.y * x2[j] + w.x * x3[j];
      r[j] = silu_f(acc);
    }
    *(float4*)&buf[ch]     = make_float4(r[0], r[1], r[2], r[3]);
    *(float4*)&buf[ch + 4] = make_float4(r[4], r[5], r[6], r[7]);
  }
  __syncthreads();
  {
    int vec = tid >> 2, part = tid & 3;
    int base = (vec < 16) ? vec * 128 : 2048 + (vec - 16) * 128;
    float s = 0.f;
    #pragma unroll
    for (int i = 0; i < 8; i++) {
      float4 v4 = *(const float4*)&buf[base + part * 32 + i * 4];
      s += v4.x * v4.x + v4.y * v4.y + v4.z * v4.z + v4.w * v4.w;
    }
    partial[tid] = s;
  }
  __syncthreads();
  if (tid < 64) {
    float tot = partial[tid * 4] + partial[tid * 4 + 1] + partial[tid * 4 + 2] + partial[tid * 4 + 3];
    float sc = rsqrtf(tot + 1e-6f);
    if (tid < 16) sc *= 0.08838834764831845f;   // * DK^-0.5 for q
    scl[tid] = sc;
  }
  __syncthreads();
  for (int cb = tid; cb < 1792; cb += 256) {
    int ch = cb * 8;
    float4 y0 = *(const float4*)&buf[ch];
    float4 y1 = *(const float4*)&buf[ch + 4];
    float sc; u16* dst;
    if (ch < 2048)      { sc = scl[ch >> 7];              dst = &qs[(size_t)row * 2048 + ch]; }
    else if (ch < 8192) { int r = ch - 2048; sc = scl[16 + (r >> 7)]; dst = &ks[(size_t)row * 6144 + r]; }
    else                { int r = ch - 8192; sc = 1.f;    dst = &vs[(size_t)row * 6144 + r]; }
    ushort4 s0, s1;
    s0.x = f2b(y0.x * sc); s0.y = f2b(y0.y * sc); s0.z = f2b(y0.z * sc); s0.w = f2b(y0.w * sc);
    s1.x = f2b(y1.x * sc); s1.y = f2b(y1.y * sc); s1.z = f2b(y1.z * sc); s1.w = f2b(y1.w * sc);
    *(ushort4*)dst = s0;
    *(ushort4*)(dst + 4) = s1;
  }
  if (tid < 16) {
    int h = tid;
    float b0 = b2f(P[prow + COL_B + h]);
    float b1 = b2f(P[prow + COL_B + 16 + h]);
    float b2 = b2f(P[prow + COL_B + 32 + h]);
    float pa = b2f(P[prow + COL_A + h]) + dt_bias[h];
    float sp = (pa > 20.f) ? pa : log1pf(__expf(pa));
    float4 bg;
    bg.x = 2.f / (1.f + __expf(-b0));
    bg.y = 2.f / (1.f + __expf(-b1));
    bg.z = 2.f / (1.f + __expf(-b2));
    bg.w = __expf(-__expf(A_log[h]) * sp);   // e = exp(g), hoisted off the scan chain
    *(float4*)&betag[((size_t)row * 16 + h) * 4] = bg;
  }
}

// ---------------- FUSED: scan (blocks 0..255) + gate GEMM (256..767) + Wo-T (768..4863) ----
// Scan is latency-bound at 1 wave/SIMD with MfmaUtil=0; the gate GEMM and Wo transpose
// have no dependency on the scan, so their waves fill the idle SIMD slots/MFMA pipe.
struct Step {
  uint4 qa;
  uint4 ka, kb, kc;
  float va, vb, vc;
  float4 bg;   // (beta1, beta2, beta3, e)
};

#define SUBSTEP(KV, VV, BBv) { \
  float k0_, k1_, k2_, k3_, k4_, k5_, k6_, k7_; \
  UNPK((KV).x, k0_, k1_); UNPK((KV).y, k2_, k3_); \
  UNPK((KV).z, k4_, k5_); UNPK((KV).w, k6_, k7_); \
  float p = ((k0_ * S0 + k1_ * S1) + (k2_ * S2 + k3_ * S3)) \
          + ((k4_ * S4 + k5_ * S5) + (k6_ * S6 + k7_ * S7)); \
  p = rowsum16(p); \
  float uu = (BBv) * ((VV) - p); \
  S0 += k0_ * uu; S1 += k1_ * uu; S2 += k2_ * uu; S3 += k3_ * uu; \
  S4 += k4_ * uu; S5 += k5_ * uu; S6 += k6_ * uu; S7 += k7_ * uu; }

__global__ __launch_bounds__(256) void scan_fuse_kernel(
    const u16* __restrict__ qs, const u16* __restrict__ ks,
    const u16* __restrict__ vs, const float* __restrict__ betag,
    float* __restrict__ os,
    const u16* __restrict__ gA, const u16* __restrict__ gBT, u16* __restrict__ gC,
    const float* __restrict__ Wo, u16* __restrict__ WoT) {
  int bid = blockIdx.x;
  int tid = threadIdx.x;
  if (bid >= 768) {
    // ---- Wo transpose tile ----
    int flat = bid - 768;
    t2048_body(Wo, WoT, (flat & 63) * 32, (flat >> 6) * 32, tid & 31, tid >> 5);
    return;
  }
  if (bid >= 256) {
    // ---- gate GEMM block: C[4096][2048] = xb @ WgT^T ----
    int flat = bid - 256;
    gemm_body<u16>(gA, gBT, gC, M_ROWS, 2048, KDIM, flat & 15, flat >> 4, tid);
    return;
  }
  // ---- scan (exact r9 body) ----
  int blk = bid;
  int vchunk = blk & 7, bh = blk >> 3;
  int h = bh & 15, b = bh >> 4;
  int c = tid >> 4, kl = tid & 15;
  int v = vchunk * 16 + c;
  float S0 = 0, S1 = 0, S2 = 0, S3 = 0, S4 = 0, S5 = 0, S6 = 0, S7 = 0;

  const size_t qbase = ((size_t)b * T_SEQ) * 2048 + h * 128 + kl * 8;
  const size_t kbase = ((size_t)b * T_SEQ) * 6144 + h * 128 + kl * 8;
  const size_t vbase = ((size_t)b * T_SEQ) * 6144 + h * 128 + v;
  const size_t obase = ((size_t)b * T_SEQ) * 2048 + h * 128 + v;
  const size_t bgbase = ((size_t)b * T_SEQ * 16 + h) * 4;

  auto loadStep = [&](Step& s, int t) {
    s.qa = *(const uint4*)&qs[qbase + (size_t)t * 2048];
    size_t rk = kbase + (size_t)t * 6144;
    s.ka = *(const uint4*)&ks[rk];
    s.kb = *(const uint4*)&ks[rk + 2048];
    s.kc = *(const uint4*)&ks[rk + 4096];
    size_t rv = vbase + (size_t)t * 6144;
    s.va = b2f(vs[rv]); s.vb = b2f(vs[rv + 2048]); s.vc = b2f(vs[rv + 4096]);
    s.bg = *(const float4*)&betag[bgbase + (size_t)t * 64];
  };
  auto compute = [&](const Step& s, int t) {
    float e = s.bg.w;
    S0 *= e; S1 *= e; S2 *= e; S3 *= e; S4 *= e; S5 *= e; S6 *= e; S7 *= e;
    SUBSTEP(s.ka, s.va, s.bg.x);
    SUBSTEP(s.kb, s.vb, s.bg.y);
    SUBSTEP(s.kc, s.vc, s.bg.z);
    float q0_, q1_, q2_, q3_, q4_, q5_, q6_, q7_;
    UNPK(s.qa.x, q0_, q1_); UNPK(s.qa.y, q2_, q3_);
    UNPK(s.qa.z, q4_, q5_); UNPK(s.qa.w, q6_, q7_);
    float p = ((q0_ * S0 + q1_ * S1) + (q2_ * S2 + q3_ * S3))
            + ((q4_ * S4 + q5_ * S5) + (q6_ * S6 + q7_ * S7));
    p = rowsum16(p);
    if (kl == 0) os[obase + (size_t)t * 2048] = p;
  };

  Step sA, sB, sC, sD;
  loadStep(sA, 0); loadStep(sB, 1);
  for (int t = 0; t < T_SEQ; t += 4) {
    loadStep(sC, t + 2); loadStep(sD, t + 3);
    compute(sA, t); compute(sB, t + 1);
    int t4 = (t + 4 < T_SEQ) ? t + 4 : T_SEQ - 1;
    int t5 = (t + 5 < T_SEQ) ? t + 5 : T_SEQ - 1;
    loadStep(sA, t4); loadStep(sB, t5);
    compute(sC, t + 2); compute(sD, t + 3);
  }
}

// ---------------- output RMS-norm * norm_w * silu(gate) -> bf16 ----------------
__global__ __launch_bounds__(256) void norm_gate_kernel(
    const float* __restrict__ os, const u16* __restrict__ gb,
    const float* __restrict__ norm_w, u16* __restrict__ ob) {
  int row = blockIdx.x, tid = threadIdx.x;
  int hh = tid >> 4, l = tid & 15;
  size_t obase = (size_t)row * 2048 + hh * 128 + l * 8;
  float4 o0 = *(const float4*)&os[obase];
  float4 o1 = *(const float4*)&os[obase + 4];
  float ss = o0.x * o0.x + o0.y * o0.y + o0.z * o0.z + o0.w * o0.w
           + o1.x * o1.x + o1.y * o1.y + o1.z * o1.z + o1.w * o1.w;
  ss = rowsum16(ss);
  float sc = rsqrtf(ss * (1.f / 128.f) + 1e-5f);
  uint4 gv = *(const uint4*)&gb[obase];
  float4 w0 = *(const float4*)&norm_w[l * 8];
  float4 w1 = *(const float4*)&norm_w[l * 8 + 4];
  float gv0 = silu_f(b2f((u16)(gv.x & 0xffffu))), gv1 = silu_f(b2f((u16)(gv.x >> 16)));
  float gv2 = silu_f(b2f((u16)(gv.y & 0xffffu))), gv3 = silu_f(b2f((u16)(gv.y >> 16)));
  float gv4 = silu_f(b2f((u16)(gv.z & 0xffffu))), gv5 = silu_f(b2f((u16)(gv.z >> 16)));
  float gv6 = silu_f(b2f((u16)(gv.w & 0xffffu))), gv7 = silu_f(b2f((u16)(gv.w >> 16)));
  ushort4 r0, r1;
  r0.x = f2b(o0.x * sc * w0.x * gv0);
  r0.y = f2b(o0.y * sc * w0.y * gv1);
  r0.z = f2b(o0.z * sc * w0.z * gv2);
  r0.w = f2b(o0.w * sc * w0.w * gv3);
  r1.x = f2b(o1.x * sc * w1.x * gv4);
  r1.y = f2b(o1.y * sc * w1.y * gv5);
  r1.z = f2b(o1.z * sc * w1.z * gv6);
  r1.w = f2b(o1.w * sc * w1.w * gv7);
  *(ushort4*)&ob[obase] = r0;
  *(ushort4*)&ob[obase + 4] = r1;
}

extern "C" void kernel_launch(void* const* d_in, const int* in_sizes, int n_in,
                              void* d_out, int out_size, void* d_ws, size_t ws_size,
                              hipStream_t stream) {
  (void)in_sizes; (void)n_in; (void)out_size; (void)ws_size;
  const float* x       = (const float*)d_in[0];
  const float* Wq      = (const float*)d_in[3];
  const float* Wk      = (const float*)d_in[4];
  const float* Wv      = (const float*)d_in[5];
  const float* Wb      = (const float*)d_in[6];
  const float* Wa      = (const float*)d_in[7];
  const float* A_log   = (const float*)d_in[8];
  const float* dt_bias = (const float*)d_in[9];
  const float* conv_q  = (const float*)d_in[10];
  const float* conv_k  = (const float*)d_in[11];
  const float* conv_v  = (const float*)d_in[12];
  const float* Wg      = (const float*)d_in[13];
  const float* norm_w  = (const float*)d_in[14];
  const float* Wo      = (const float*)d_in[15];

  // ---- workspace layout with lifetime-based reuse (~250.5 MB peak) ----
  char* ws = (char*)d_ws;
  constexpr size_t SZ_XB    = (size_t)M_ROWS * KDIM * 2;      //  16 MB
  constexpr size_t SZ_WCAT  = (size_t)N1B * KDIM * 2;         //  56.5 MB (then ks)
  constexpr size_t SZ_P1    = (size_t)M_ROWS * N1B * 2;       // 113 MB   (then os/WgT/gb/ob/WoT)
  constexpr size_t SZ_QS    = (size_t)M_ROWS * 2048 * 2;      //  16 MB
  constexpr size_t SZ_VS    = (size_t)M_ROWS * 6144 * 2;      //  48 MB

  u16*   xb    = (u16*)(ws);
  u16*   WcatT = (u16*)(ws + SZ_XB);
  u16*   P1    = (u16*)(ws + SZ_XB + SZ_WCAT);
  u16*   qs    = (u16*)(ws + SZ_XB + SZ_WCAT + SZ_P1);
  u16*   vs    = (u16*)(ws + SZ_XB + SZ_WCAT + SZ_P1 + SZ_QS);
  float* betag = (float*)(ws + SZ_XB + SZ_WCAT + SZ_P1 + SZ_QS + SZ_VS);  // 1 MB: [row][16] float4
  // aliases (sequential stream => safe):
  u16*   ks  = WcatT;                                   // after gemm1, WcatT dead (48 <= 56.5 MB)
  char*  rp  = (char*)P1;                               // after conv_act, P1 dead
  float* os  = (float*)(rp);                            // 32 MB
  u16*   WgT = (u16*)(rp + 33554432);                   // 8 MB
  u16*   gb  = (u16*)(rp + 33554432 + 8388608);         // 16 MB
  u16*   ob  = (u16*)(rp + 33554432 + 8388608 + 16777216);            // 16 MB
  u16*   WoT = (u16*)(rp + 33554432 + 8388608 + 16777216 + 16777216); // 8 MB (80 <= 113 MB)

  cvt_x_kernel<<<(M_ROWS * KDIM) / 1024, 256, 0, stream>>>(x, xb);
  wcat_t_kernel<<<dim3(64, N1B / 32), dim3(32, 8), 0, stream>>>(Wq, Wk, Wv, Wb, Wa, WcatT);
  gemm_bt_kernel<u16><<<dim3(N1B / 128, M_ROWS / 128), 256, 0, stream>>>(xb, WcatT, P1,
                                                                         M_ROWS, N1B, KDIM);
  conv_act_kernel<<<M_ROWS, 256, 0, stream>>>(P1, conv_q, conv_k, conv_v, A_log, dt_bias,
                                              qs, ks, vs, betag);
  t2048_kernel<<<dim3(64, 64), dim3(32, 8), 0, stream>>>(Wg, WgT);
  // fused: scan (256) + gate gemm (512) + Wo transpose (4096)
  scan_fuse_kernel<<<256 + 512 + 4096, 256, 0, stream>>>(qs, ks, vs, betag, os,
                                                         xb, WgT, gb, Wo, WoT);
  norm_gate_kernel<<<M_ROWS, 256, 0, stream>>>(os, gb, norm_w, ob);
  gemm_bt_kernel<float><<<dim3(2048 / 128, M_ROWS / 128), 256, 0, stream>>>(ob, WoT, (float*)d_out,
                                                                            M_ROWS, 2048, KDIM);
}